// Round 4
// baseline (1338.268 us; speedup 1.0000x reference)
//
#include <hip/hip_runtime.h>

#define EPS 1e-10f
#define NITERS 20
#define NN (1024*1024)

typedef __attribute__((ext_vector_type(8))) short bf16x8;
typedef __attribute__((ext_vector_type(4))) float f32x4;

__device__ __forceinline__ unsigned short f2bf(float f) {
  unsigned int x = __builtin_bit_cast(unsigned int, f);
  x += 0x7fffu + ((x >> 16) & 1u);   // round-to-nearest-even
  return (unsigned short)(x >> 16);
}
__device__ __forceinline__ float bf2f(short s) {
  return __builtin_bit_cast(float, ((unsigned int)(unsigned short)s) << 16);
}

// Per-matrix barrier: 16 blocks, generation-counted (target = 16*gen).
// Release fence before arrival; device-scope spin; acquire fence (L1 inv) after.
__device__ __forceinline__ void mat_barrier(unsigned* c, unsigned target) {
  __syncthreads();
  if (threadIdx.x == 0) {
    __threadfence();
    atomicAdd(c, 1u);
    while (__hip_atomic_load(c, __ATOMIC_RELAXED, __HIP_MEMORY_SCOPE_AGENT) < target) {
      __builtin_amdgcn_s_sleep(1);
    }
    __threadfence();
  }
  __syncthreads();
}

// ---------------------------------------------------------------------------
// Persistent cooperative Sinkhorn: gumbel->K(bf16), 20 iterations, P^T emit.
// grid 256 x 512. Block bid: matrix-in-group = bid&15 (all 16 of its blocks
// share bid&7 -> same XCD), chunk = bid>>4 (64 rows). 2 groups of 16 matrices
// so per-XCD K working set = 4 MiB (~L2).
__global__ __launch_bounds__(512) void sinkhorn_coop(const float* __restrict__ u,
                                                     const float* __restrict__ la,
                                                     unsigned short* __restrict__ Kb,
                                                     float* __restrict__ pvA,
                                                     float* __restrict__ pvB,
                                                     unsigned short* __restrict__ Pt,
                                                     unsigned* __restrict__ cnt) {
  int bid = blockIdx.x;
  int tid = threadIdx.x;
  int l = tid & 63, w = tid >> 6;          // 8 waves
  int mloc = bid & 15;
  int ch = bid >> 4;
  int r0 = ch << 6;

  __shared__ float smem[8][1024];          // 32 KB wave col-partials
  __shared__ float v_lds[1024];
  __shared__ float u_lds[64];
  __shared__ unsigned short tile[64][66];

  for (int g = 0; g < 2; ++g) {
    int mat = g * 16 + mloc;
    const float* ub = u + (size_t)mat * NN;
    unsigned short* Ks = Kb + (size_t)mat * NN;
    float* pA = pvA + ((size_t)mat << 14);
    float* pB = pvB + ((size_t)mat << 14);
    unsigned* c = cnt + mat;

    // ---- phase 0: gumbel -> K bf16; col partials with u-potential = 1
    {
      float colacc[16];
#pragma unroll
      for (int k2 = 0; k2 < 16; ++k2) colacc[k2] = 0.f;
#pragma unroll 1
      for (int p = 0; p < 8; ++p) {
        int row = r0 + (p << 3) + w;
        const f32x4* u4 = (const f32x4*)(ub + (size_t)row * 1024 + l * 16);
        const f32x4* la4 = (const f32x4*)(la + (size_t)row * 1024 + l * 16);
        float kf[16];
#pragma unroll
        for (int q = 0; q < 4; ++q) {
          f32x4 uv = __builtin_nontemporal_load(u4 + q);
          f32x4 lv = __builtin_nontemporal_load(la4 + q);
#pragma unroll
          for (int e = 0; e < 4; ++e)
            kf[q * 4 + e] = expf(lv[e]) / (EPS - logf(uv[e] + EPS));
        }
        bf16x8 o0, o1;
#pragma unroll
        for (int j = 0; j < 8; ++j) {
          o0[j] = (short)f2bf(kf[j]);
          o1[j] = (short)f2bf(kf[8 + j]);
          colacc[j] += kf[j];
          colacc[8 + j] += kf[8 + j];
        }
        bf16x8* kp = (bf16x8*)(Ks + (size_t)row * 1024 + l * 16);
        kp[0] = o0; kp[1] = o1;
      }
#pragma unroll
      for (int k2 = 0; k2 < 16; ++k2) smem[w][l * 16 + k2] = colacc[k2];
      __syncthreads();
      if (tid < 256) {
        float4 s = make_float4(0.f, 0.f, 0.f, 0.f);
#pragma unroll
        for (int ww = 0; ww < 8; ++ww) {
          float4 a = *(float4*)&smem[ww][tid * 4];
          s.x += a.x; s.y += a.y; s.z += a.z; s.w += a.w;
        }
        *(float4*)&pA[(ch << 10) + tid * 4] = s;
      }
      mat_barrier(c, 16u);
    }

    // ---- 19 fused iterations (v_t, u_t, partials for v_{t+1})
    const float* pin = pA;
    float* pout = pB;
#pragma unroll 1
    for (int t = 1; t < NITERS; ++t) {
      {
        const float2* p2 = (const float2*)pin;
        float2 s = make_float2(0.f, 0.f);
#pragma unroll
        for (int cch = 0; cch < 16; ++cch) {
          float2 a = p2[cch * 512 + tid];
          s.x += a.x; s.y += a.y;
        }
        v_lds[2 * tid] = 1.f / s.x;
        v_lds[2 * tid + 1] = 1.f / s.y;
      }
      __syncthreads();
      float vreg[16];
#pragma unroll
      for (int k2 = 0; k2 < 16; ++k2) vreg[k2] = v_lds[l * 16 + k2];

      float colacc[16];
#pragma unroll
      for (int k2 = 0; k2 < 16; ++k2) colacc[k2] = 0.f;
#pragma unroll 2
      for (int p = 0; p < 8; ++p) {
        int row = r0 + (p << 3) + w;
        const bf16x8* kp = (const bf16x8*)(Ks + (size_t)row * 1024 + l * 16);
        bf16x8 k0 = kp[0], k1 = kp[1];
        float kf[16];
#pragma unroll
        for (int j = 0; j < 8; ++j) { kf[j] = bf2f(k0[j]); kf[8 + j] = bf2f(k1[j]); }
        float dot = 0.f;
#pragma unroll
        for (int k2 = 0; k2 < 16; ++k2) dot += kf[k2] * vreg[k2];
#pragma unroll
        for (int m = 1; m < 64; m <<= 1) dot += __shfl_xor(dot, m, 64);
        float ui = 1.0f / dot;
#pragma unroll
        for (int k2 = 0; k2 < 16; ++k2) colacc[k2] += kf[k2] * ui;
      }
#pragma unroll
      for (int k2 = 0; k2 < 16; ++k2) smem[w][l * 16 + k2] = colacc[k2];
      __syncthreads();
      if (tid < 256) {
        float4 s = make_float4(0.f, 0.f, 0.f, 0.f);
#pragma unroll
        for (int ww = 0; ww < 8; ++ww) {
          float4 a = *(float4*)&smem[ww][tid * 4];
          s.x += a.x; s.y += a.y; s.z += a.z; s.w += a.w;
        }
        *(float4*)&pout[(ch << 10) + tid * 4] = s;
      }
      mat_barrier(c, 16u * (unsigned)(t + 1));
      const float* tp = pout; pout = (float*)pin; pin = tp;
    }

    // ---- final: v_20, u_20, Pt[m][n] = K[n][m] * u[n] * v[m] (bf16)
    {
      const float2* p2 = (const float2*)pin;
      float2 s = make_float2(0.f, 0.f);
#pragma unroll
      for (int cch = 0; cch < 16; ++cch) {
        float2 a = p2[cch * 512 + tid];
        s.x += a.x; s.y += a.y;
      }
      v_lds[2 * tid] = 1.f / s.x;
      v_lds[2 * tid + 1] = 1.f / s.y;
    }
    __syncthreads();
    {
      float vreg[16];
#pragma unroll
      for (int k2 = 0; k2 < 16; ++k2) vreg[k2] = v_lds[l * 16 + k2];
#pragma unroll 1
      for (int p = 0; p < 8; ++p) {
        int row = r0 + (p << 3) + w;
        const bf16x8* kp = (const bf16x8*)(Ks + (size_t)row * 1024 + l * 16);
        bf16x8 k0 = kp[0], k1 = kp[1];
        float dot = 0.f;
#pragma unroll
        for (int j = 0; j < 8; ++j) dot += bf2f(k0[j]) * vreg[j] + bf2f(k1[j]) * vreg[8 + j];
#pragma unroll
        for (int m = 1; m < 64; m <<= 1) dot += __shfl_xor(dot, m, 64);
        if (l == 0) u_lds[(p << 3) + w] = 1.0f / dot;
      }
    }
    __syncthreads();
    {
      unsigned short* Pb = Pt + (size_t)mat * NN;
      int cc = tid & 63, r8 = tid >> 6;
#pragma unroll 1
      for (int mt = 0; mt < 16; ++mt) {
        int m0 = mt << 6;
#pragma unroll
        for (int p = 0; p < 8; ++p) {
          int rr = (p << 3) + r8;
          float val = bf2f((short)Ks[(size_t)(r0 + rr) * 1024 + m0 + cc]) * u_lds[rr] * v_lds[m0 + cc];
          tile[rr][cc] = f2bf(val);
        }
        __syncthreads();
#pragma unroll
        for (int p = 0; p < 8; ++p) {
          int rr = (p << 3) + r8;
          Pb[(size_t)(m0 + rr) * 1024 + r0 + cc] = tile[cc][rr];
        }
        __syncthreads();
      }
    }
  }
}

// ---------------------------------------------------------------------------
__global__ __launch_bounds__(256) void cvt_x(const float4* __restrict__ x4,
                                             unsigned short* __restrict__ xb) {
  int gid = blockIdx.x * 256 + threadIdx.x;      // 2,097,152 float4s
  float4 v = x4[gid];
  ushort4 o;
  o.x = f2bf(v.x); o.y = f2bf(v.y); o.z = f2bf(v.z); o.w = f2bf(v.w);
  *(ushort4*)&xb[(size_t)gid * 4] = o;
}

// C[d][m] = sum_n A[d][n] * B[n][m]; A = xb (row-major), Bt = P^T.
// 128x128 tile, 4 waves, 16x16x32 MFMA, global_load_lds(16B), XCD swizzle.
__global__ __launch_bounds__(256) void gemm_bf16(const unsigned short* __restrict__ xb,
                                                 const unsigned short* __restrict__ Pt,
                                                 float* __restrict__ out) {
  int bid = blockIdx.x;                          // 2048 = 8 XCD * 256
  int lid = (bid & 7) * 256 + (bid >> 3);        // bijective XCD swizzle
  int sb = lid >> 6;
  int tm = (lid >> 3) & 7;
  int tn = lid & 7;
  int b = sb & 7;
  const unsigned short* A = xb + (size_t)b * NN;
  const unsigned short* Bt = Pt + (size_t)sb * NN;
  float* C = out + (size_t)sb * NN;

  __shared__ unsigned short lA[128 * 32];
  __shared__ unsigned short lB[128 * 32];

  int tid = threadIdx.x;
  int lane = tid & 63;
  int w = tid >> 6;
  int wm = (w >> 1) << 6;
  int wn = (w & 1) << 6;

  f32x4 acc[4][4] = {};

  int lr = tid >> 2;
  int lk = (tid & 3) << 3;
  const unsigned short* gA0 = A + (size_t)(tm * 128 + lr) * 1024 + lk;
  const unsigned short* gB0 = Bt + (size_t)(tn * 128 + lr) * 1024 + lk;

  for (int k0 = 0; k0 < 1024; k0 += 32) {
    __builtin_amdgcn_global_load_lds((const __attribute__((address_space(1))) void*)(gA0 + k0),
                                     (__attribute__((address_space(3))) void*)&lA[tid * 8], 16, 0, 0);
    __builtin_amdgcn_global_load_lds((const __attribute__((address_space(1))) void*)(gA0 + 64 * 1024 + k0),
                                     (__attribute__((address_space(3))) void*)&lA[2048 + tid * 8], 16, 0, 0);
    __builtin_amdgcn_global_load_lds((const __attribute__((address_space(1))) void*)(gB0 + k0),
                                     (__attribute__((address_space(3))) void*)&lB[tid * 8], 16, 0, 0);
    __builtin_amdgcn_global_load_lds((const __attribute__((address_space(1))) void*)(gB0 + 64 * 1024 + k0),
                                     (__attribute__((address_space(3))) void*)&lB[2048 + tid * 8], 16, 0, 0);
    __syncthreads();

    int kg = (lane >> 4) << 3;
    int rr = lane & 15;
    bf16x8 af[4], bfr[4];
#pragma unroll
    for (int mt = 0; mt < 4; ++mt)
      af[mt] = *(const bf16x8*)&lA[(wm + mt * 16 + rr) * 32 + kg];
#pragma unroll
    for (int nt = 0; nt < 4; ++nt)
      bfr[nt] = *(const bf16x8*)&lB[(wn + nt * 16 + rr) * 32 + kg];
#pragma unroll
    for (int mt = 0; mt < 4; ++mt)
#pragma unroll
      for (int nt = 0; nt < 4; ++nt)
        acc[mt][nt] = __builtin_amdgcn_mfma_f32_16x16x32_bf16(af[mt], bfr[nt], acc[mt][nt], 0, 0, 0);
    __syncthreads();
  }

  int col0 = lane & 15;
  int row0 = (lane >> 4) << 2;
#pragma unroll
  for (int mt = 0; mt < 4; ++mt) {
#pragma unroll
    for (int nt = 0; nt < 4; ++nt) {
      int row = tm * 128 + wm + mt * 16 + row0;
      int col = tn * 128 + wn + nt * 16 + col0;
#pragma unroll
      for (int r = 0; r < 4; ++r)
        C[(size_t)(row + r) * 1024 + col] = acc[mt][nt][r];
    }
  }
}

extern "C" void kernel_launch(void* const* d_in, const int* in_sizes, int n_in,
                              void* d_out, int out_size, void* d_ws, size_t ws_size,
                              hipStream_t stream) {
  (void)in_sizes; (void)n_in; (void)out_size;
  const float* x  = (const float*)d_in[0];   // (B=8, D=1024, N=1024)
  const float* la = (const float*)d_in[1];   // (N, N)
  const float* u  = (const float*)d_in[2];   // (S=4, B=8, N, N)
  float* out = (float*)d_out;                // (S, B, D, N)

  char* ws = (char*)d_ws;
  unsigned short* Kb = (unsigned short*)(ws);               // 64 MiB bf16 K
  unsigned short* Pt = (unsigned short*)(ws + 67108864);    // 64 MiB bf16 P^T
  unsigned short* xb = (unsigned short*)(ws + 134217728);   // 16 MiB bf16 x
  float* pvA         = (float*)(ws + 150994944);            // 2 MiB col partials
  float* pvB         = (float*)(ws + 153092096);            // 2 MiB col partials
  unsigned* cnt      = (unsigned*)(ws + 155189248);         // 128 B barriers
  if (ws_size < 155189376) return;  // fail loudly rather than corrupt

  hipMemsetAsync(cnt, 0, 128, stream);
  cvt_x<<<8192, 256, 0, stream>>>((const float4*)x, xb);

  void* args[] = {(void*)&u, (void*)&la, (void*)&Kb, (void*)&pvA,
                  (void*)&pvB, (void*)&Pt, (void*)&cnt};
  hipLaunchCooperativeKernel((void*)sinkhorn_coop, dim3(256), dim3(512),
                             args, 0, stream);

  gemm_bf16<<<2048, 256, 0, stream>>>(xb, Pt, out);
}

// Round 5
// 981.425 us; speedup vs baseline: 1.3636x; 1.3636x over previous
//
#include <hip/hip_runtime.h>

#define EPS 1e-10f
#define NITERS 20
#define NN (1024*1024)

typedef __attribute__((ext_vector_type(8))) short bf16x8;
typedef __attribute__((ext_vector_type(4))) float f32x4;

__device__ __forceinline__ unsigned short f2bf(float f) {
  unsigned int x = __builtin_bit_cast(unsigned int, f);
  x += 0x7fffu + ((x >> 16) & 1u);   // round-to-nearest-even
  return (unsigned short)(x >> 16);
}
__device__ __forceinline__ float bf2f(short s) {
  return __builtin_bit_cast(float, ((unsigned int)(unsigned short)s) << 16);
}

// Per-matrix barrier, contention-hardened: sync base = 4KB-strided per matrix.
// base[0] = arrival counter (atomicAdd); base[64] = release word (own line,
// read-mostly: 15 pollers, written once per generation by the last arriver).
__device__ __forceinline__ void mat_barrier(unsigned* base, unsigned target) {
  __syncthreads();
  if (threadIdx.x == 0) {
    __threadfence();                               // release pv writes
    unsigned old = atomicAdd(base, 1u);
    if (old == target - 1u) {
      __hip_atomic_store(base + 64, target, __ATOMIC_RELAXED, __HIP_MEMORY_SCOPE_AGENT);
    } else {
      while (__hip_atomic_load(base + 64, __ATOMIC_RELAXED, __HIP_MEMORY_SCOPE_AGENT) < target) {
        __builtin_amdgcn_s_sleep(32);              // ~2048 cy backoff
      }
    }
    __threadfence();                               // acquire (L1 inv)
  }
  __syncthreads();
}

// ---------------------------------------------------------------------------
// Persistent cooperative Sinkhorn: gumbel->K(bf16), 20 iterations, P^T emit.
// grid 256 x 512. Block bid: matrix-in-group = bid&15 (all 16 of its blocks
// share bid&7 -> same XCD), chunk = bid>>4 (64 rows). 2 groups of 16 matrices
// so per-XCD K working set = 4 MiB (~L2).
__global__ __launch_bounds__(512) void sinkhorn_coop(const float* __restrict__ u,
                                                     const float* __restrict__ la,
                                                     unsigned short* __restrict__ Kb,
                                                     float* __restrict__ pvA,
                                                     float* __restrict__ pvB,
                                                     unsigned short* __restrict__ Pt,
                                                     unsigned* __restrict__ cnt) {
  int bid = blockIdx.x;
  int tid = threadIdx.x;
  int l = tid & 63, w = tid >> 6;          // 8 waves
  int mloc = bid & 15;
  int ch = bid >> 4;
  int r0 = ch << 6;

  __shared__ float smem[8][1024];          // 32 KB wave col-partials
  __shared__ float v_lds[1024];
  __shared__ float u_lds[64];
  __shared__ unsigned short tile[64][66];

  for (int g = 0; g < 2; ++g) {
    int mat = g * 16 + mloc;
    const float* ub = u + (size_t)mat * NN;
    unsigned short* Ks = Kb + (size_t)mat * NN;
    float* pA = pvA + ((size_t)mat << 14);
    float* pB = pvB + ((size_t)mat << 14);
    unsigned* c = cnt + (size_t)mat * 1024;        // 4 KB stride per matrix

    // ---- phase 0: gumbel -> K bf16; col partials with u-potential = 1
    {
      float colacc[16];
#pragma unroll
      for (int k2 = 0; k2 < 16; ++k2) colacc[k2] = 0.f;
#pragma unroll 1
      for (int p = 0; p < 8; ++p) {
        int row = r0 + (p << 3) + w;
        const f32x4* u4 = (const f32x4*)(ub + (size_t)row * 1024 + l * 16);
        const f32x4* la4 = (const f32x4*)(la + (size_t)row * 1024 + l * 16);
        float kf[16];
#pragma unroll
        for (int q = 0; q < 4; ++q) {
          f32x4 uv = __builtin_nontemporal_load(u4 + q);
          f32x4 lv = __builtin_nontemporal_load(la4 + q);
#pragma unroll
          for (int e = 0; e < 4; ++e)
            kf[q * 4 + e] = expf(lv[e]) / (EPS - logf(uv[e] + EPS));
        }
        bf16x8 o0, o1;
#pragma unroll
        for (int j = 0; j < 8; ++j) {
          o0[j] = (short)f2bf(kf[j]);
          o1[j] = (short)f2bf(kf[8 + j]);
          colacc[j] += kf[j];
          colacc[8 + j] += kf[8 + j];
        }
        bf16x8* kp = (bf16x8*)(Ks + (size_t)row * 1024 + l * 16);
        kp[0] = o0; kp[1] = o1;
      }
#pragma unroll
      for (int k2 = 0; k2 < 16; ++k2) smem[w][l * 16 + k2] = colacc[k2];
      __syncthreads();
      if (tid < 256) {
        float4 s = make_float4(0.f, 0.f, 0.f, 0.f);
#pragma unroll
        for (int ww = 0; ww < 8; ++ww) {
          float4 a = *(float4*)&smem[ww][tid * 4];
          s.x += a.x; s.y += a.y; s.z += a.z; s.w += a.w;
        }
        *(float4*)&pA[(ch << 10) + tid * 4] = s;
      }
      mat_barrier(c, 16u);
    }

    // ---- 19 fused iterations (v_t, u_t, partials for v_{t+1})
    const float* pin = pA;
    float* pout = pB;
#pragma unroll 1
    for (int t = 1; t < NITERS; ++t) {
      {
        const float2* p2 = (const float2*)pin;
        float2 s = make_float2(0.f, 0.f);
#pragma unroll
        for (int cch = 0; cch < 16; ++cch) {
          float2 a = p2[cch * 512 + tid];
          s.x += a.x; s.y += a.y;
        }
        v_lds[2 * tid] = 1.f / s.x;
        v_lds[2 * tid + 1] = 1.f / s.y;
      }
      __syncthreads();
      float vreg[16];
#pragma unroll
      for (int k2 = 0; k2 < 16; ++k2) vreg[k2] = v_lds[l * 16 + k2];

      float colacc[16];
#pragma unroll
      for (int k2 = 0; k2 < 16; ++k2) colacc[k2] = 0.f;
#pragma unroll 2
      for (int p = 0; p < 8; ++p) {
        int row = r0 + (p << 3) + w;
        const bf16x8* kp = (const bf16x8*)(Ks + (size_t)row * 1024 + l * 16);
        bf16x8 k0 = kp[0], k1 = kp[1];
        float kf[16];
#pragma unroll
        for (int j = 0; j < 8; ++j) { kf[j] = bf2f(k0[j]); kf[8 + j] = bf2f(k1[j]); }
        float dot = 0.f;
#pragma unroll
        for (int k2 = 0; k2 < 16; ++k2) dot += kf[k2] * vreg[k2];
#pragma unroll
        for (int m = 1; m < 64; m <<= 1) dot += __shfl_xor(dot, m, 64);
        float ui = 1.0f / dot;
#pragma unroll
        for (int k2 = 0; k2 < 16; ++k2) colacc[k2] += kf[k2] * ui;
      }
#pragma unroll
      for (int k2 = 0; k2 < 16; ++k2) smem[w][l * 16 + k2] = colacc[k2];
      __syncthreads();
      if (tid < 256) {
        float4 s = make_float4(0.f, 0.f, 0.f, 0.f);
#pragma unroll
        for (int ww = 0; ww < 8; ++ww) {
          float4 a = *(float4*)&smem[ww][tid * 4];
          s.x += a.x; s.y += a.y; s.z += a.z; s.w += a.w;
        }
        *(float4*)&pout[(ch << 10) + tid * 4] = s;
      }
      mat_barrier(c, 16u * (unsigned)(t + 1));
      const float* tp = pout; pout = (float*)pin; pin = tp;
    }

    // ---- final: v_20, u_20, Pt[m][n] = K[n][m] * u[n] * v[m] (bf16)
    {
      const float2* p2 = (const float2*)pin;
      float2 s = make_float2(0.f, 0.f);
#pragma unroll
      for (int cch = 0; cch < 16; ++cch) {
        float2 a = p2[cch * 512 + tid];
        s.x += a.x; s.y += a.y;
      }
      v_lds[2 * tid] = 1.f / s.x;
      v_lds[2 * tid + 1] = 1.f / s.y;
    }
    __syncthreads();
    {
      float vreg[16];
#pragma unroll
      for (int k2 = 0; k2 < 16; ++k2) vreg[k2] = v_lds[l * 16 + k2];
#pragma unroll 1
      for (int p = 0; p < 8; ++p) {
        int row = r0 + (p << 3) + w;
        const bf16x8* kp = (const bf16x8*)(Ks + (size_t)row * 1024 + l * 16);
        bf16x8 k0 = kp[0], k1 = kp[1];
        float dot = 0.f;
#pragma unroll
        for (int j = 0; j < 8; ++j) dot += bf2f(k0[j]) * vreg[j] + bf2f(k1[j]) * vreg[8 + j];
#pragma unroll
        for (int m = 1; m < 64; m <<= 1) dot += __shfl_xor(dot, m, 64);
        if (l == 0) u_lds[(p << 3) + w] = 1.0f / dot;
      }
    }
    __syncthreads();
    {
      unsigned short* Pb = Pt + (size_t)mat * NN;
      int cc = tid & 63, r8 = tid >> 6;
#pragma unroll 1
      for (int mt = 0; mt < 16; ++mt) {
        int m0 = mt << 6;
#pragma unroll
        for (int p = 0; p < 8; ++p) {
          int rr = (p << 3) + r8;
          float val = bf2f((short)Ks[(size_t)(r0 + rr) * 1024 + m0 + cc]) * u_lds[rr] * v_lds[m0 + cc];
          tile[rr][cc] = f2bf(val);
        }
        __syncthreads();
#pragma unroll
        for (int p = 0; p < 8; ++p) {
          int rr = (p << 3) + r8;
          Pb[(size_t)(m0 + rr) * 1024 + r0 + cc] = tile[cc][rr];
        }
        __syncthreads();
      }
    }
  }
}

// ---------------------------------------------------------------------------
__global__ __launch_bounds__(256) void cvt_x(const float4* __restrict__ x4,
                                             unsigned short* __restrict__ xb) {
  int gid = blockIdx.x * 256 + threadIdx.x;      // 2,097,152 float4s
  float4 v = x4[gid];
  ushort4 o;
  o.x = f2bf(v.x); o.y = f2bf(v.y); o.z = f2bf(v.z); o.w = f2bf(v.w);
  *(ushort4*)&xb[(size_t)gid * 4] = o;
}

// C[d][m] = sum_n A[d][n] * B[n][m]; A = xb (row-major), Bt = P^T.
// 128x128 tile, 4 waves, 16x16x32 MFMA, global_load_lds(16B), XCD swizzle.
__global__ __launch_bounds__(256) void gemm_bf16(const unsigned short* __restrict__ xb,
                                                 const unsigned short* __restrict__ Pt,
                                                 float* __restrict__ out) {
  int bid = blockIdx.x;                          // 2048 = 8 XCD * 256
  int lid = (bid & 7) * 256 + (bid >> 3);        // bijective XCD swizzle
  int sb = lid >> 6;
  int tm = (lid >> 3) & 7;
  int tn = lid & 7;
  int b = sb & 7;
  const unsigned short* A = xb + (size_t)b * NN;
  const unsigned short* Bt = Pt + (size_t)sb * NN;
  float* C = out + (size_t)sb * NN;

  __shared__ unsigned short lA[128 * 32];
  __shared__ unsigned short lB[128 * 32];

  int tid = threadIdx.x;
  int lane = tid & 63;
  int w = tid >> 6;
  int wm = (w >> 1) << 6;
  int wn = (w & 1) << 6;

  f32x4 acc[4][4] = {};

  int lr = tid >> 2;
  int lk = (tid & 3) << 3;
  const unsigned short* gA0 = A + (size_t)(tm * 128 + lr) * 1024 + lk;
  const unsigned short* gB0 = Bt + (size_t)(tn * 128 + lr) * 1024 + lk;

  for (int k0 = 0; k0 < 1024; k0 += 32) {
    __builtin_amdgcn_global_load_lds((const __attribute__((address_space(1))) void*)(gA0 + k0),
                                     (__attribute__((address_space(3))) void*)&lA[tid * 8], 16, 0, 0);
    __builtin_amdgcn_global_load_lds((const __attribute__((address_space(1))) void*)(gA0 + 64 * 1024 + k0),
                                     (__attribute__((address_space(3))) void*)&lA[2048 + tid * 8], 16, 0, 0);
    __builtin_amdgcn_global_load_lds((const __attribute__((address_space(1))) void*)(gB0 + k0),
                                     (__attribute__((address_space(3))) void*)&lB[tid * 8], 16, 0, 0);
    __builtin_amdgcn_global_load_lds((const __attribute__((address_space(1))) void*)(gB0 + 64 * 1024 + k0),
                                     (__attribute__((address_space(3))) void*)&lB[2048 + tid * 8], 16, 0, 0);
    __syncthreads();

    int kg = (lane >> 4) << 3;
    int rr = lane & 15;
    bf16x8 af[4], bfr[4];
#pragma unroll
    for (int mt = 0; mt < 4; ++mt)
      af[mt] = *(const bf16x8*)&lA[(wm + mt * 16 + rr) * 32 + kg];
#pragma unroll
    for (int nt = 0; nt < 4; ++nt)
      bfr[nt] = *(const bf16x8*)&lB[(wn + nt * 16 + rr) * 32 + kg];
#pragma unroll
    for (int mt = 0; mt < 4; ++mt)
#pragma unroll
      for (int nt = 0; nt < 4; ++nt)
        acc[mt][nt] = __builtin_amdgcn_mfma_f32_16x16x32_bf16(af[mt], bfr[nt], acc[mt][nt], 0, 0, 0);
    __syncthreads();
  }

  int col0 = lane & 15;
  int row0 = (lane >> 4) << 2;
#pragma unroll
  for (int mt = 0; mt < 4; ++mt) {
#pragma unroll
    for (int nt = 0; nt < 4; ++nt) {
      int row = tm * 128 + wm + mt * 16 + row0;
      int col = tn * 128 + wn + nt * 16 + col0;
#pragma unroll
      for (int r = 0; r < 4; ++r)
        C[(size_t)(row + r) * 1024 + col] = acc[mt][nt][r];
    }
  }
}

extern "C" void kernel_launch(void* const* d_in, const int* in_sizes, int n_in,
                              void* d_out, int out_size, void* d_ws, size_t ws_size,
                              hipStream_t stream) {
  (void)in_sizes; (void)n_in; (void)out_size;
  const float* x  = (const float*)d_in[0];   // (B=8, D=1024, N=1024)
  const float* la = (const float*)d_in[1];   // (N, N)
  const float* u  = (const float*)d_in[2];   // (S=4, B=8, N, N)
  float* out = (float*)d_out;                // (S, B, D, N)

  char* ws = (char*)d_ws;
  unsigned short* Kb = (unsigned short*)(ws);               // 64 MiB bf16 K
  unsigned short* Pt = (unsigned short*)(ws + 67108864);    // 64 MiB bf16 P^T
  unsigned short* xb = (unsigned short*)(ws + 134217728);   // 16 MiB bf16 x
  float* pvA         = (float*)(ws + 150994944);            // 2 MiB col partials
  float* pvB         = (float*)(ws + 153092096);            // 2 MiB col partials
  unsigned* cnt      = (unsigned*)(ws + 155189248);         // 128 KiB sync (4KB/matrix)
  if (ws_size < 155320320) return;  // fail loudly rather than corrupt

  hipMemsetAsync(cnt, 0, 131072, stream);
  cvt_x<<<8192, 256, 0, stream>>>((const float4*)x, xb);

  void* args[] = {(void*)&u, (void*)&la, (void*)&Kb, (void*)&pvA,
                  (void*)&pvB, (void*)&Pt, (void*)&cnt};
  hipLaunchCooperativeKernel((void*)sinkhorn_coop, dim3(256), dim3(512),
                             args, 0, stream);

  gemm_bf16<<<2048, 256, 0, stream>>>(xb, Pt, out);
}

// Round 7
// 526.926 us; speedup vs baseline: 2.5398x; 1.8625x over previous
//
#include <hip/hip_runtime.h>

#define EPS 1e-10f
#define NITERS 20
#define NN (1024*1024)

typedef __attribute__((ext_vector_type(8))) short bf16x8;
typedef __attribute__((ext_vector_type(4))) float f32x4;

__device__ __forceinline__ unsigned short f2bf(float f) {
  unsigned int x = __builtin_bit_cast(unsigned int, f);
  x += 0x7fffu + ((x >> 16) & 1u);   // round-to-nearest-even
  return (unsigned short)(x >> 16);
}
__device__ __forceinline__ float bf2f(short s) {
  return __builtin_bit_cast(float, ((unsigned int)(unsigned short)s) << 16);
}

// Coherence-point 8B store/load (agent scope, relaxed). These bypass the
// non-coherent L1/L2 without invalidating them -> K stays L2-resident.
__device__ __forceinline__ void pv_store2(float* p, float a, float b) {
  unsigned long long v = (unsigned long long)__builtin_bit_cast(unsigned int, a)
                       | ((unsigned long long)__builtin_bit_cast(unsigned int, b) << 32);
  __hip_atomic_store((unsigned long long*)p, v, __ATOMIC_RELAXED, __HIP_MEMORY_SCOPE_AGENT);
}
__device__ __forceinline__ float2 pv_load2(const float* p) {
  unsigned long long v = __hip_atomic_load((const unsigned long long*)p,
                                           __ATOMIC_RELAXED, __HIP_MEMORY_SCOPE_AGENT);
  float2 r;
  r.x = __builtin_bit_cast(float, (unsigned int)(v & 0xffffffffull));
  r.y = __builtin_bit_cast(float, (unsigned int)(v >> 32));
  return r;
}

// Fence-free per-matrix barrier (16 blocks). NO __threadfence: agent-scope
// acquire would buffer_inv the L2 and evict K. All cross-block data travels
// via coherence-point atomics; __syncthreads() drains vmcnt (compiler emits
// s_waitcnt vmcnt(0) before s_barrier) so the block's pv stores are globally
// visible before thread 0 arrives.
__device__ __forceinline__ void mat_barrier(unsigned* c, unsigned target) {
  __syncthreads();
  if (threadIdx.x == 0) {
    __hip_atomic_fetch_add(c, 1u, __ATOMIC_RELAXED, __HIP_MEMORY_SCOPE_AGENT);
    while (__hip_atomic_load(c, __ATOMIC_RELAXED, __HIP_MEMORY_SCOPE_AGENT) < target) {
      __builtin_amdgcn_s_sleep(8);               // ~512 cy backoff
    }
  }
  __syncthreads();
}

// ---------------------------------------------------------------------------
// Persistent cooperative Sinkhorn: gumbel->K(bf16), 20 iterations, P^T emit.
// grid 256 x 512. mloc = bid&15, chunk = bid>>4 (64 rows); 2 groups of 16
// matrices -> per-XCD K working set 4 MiB (~L2). K is block-private (each
// block reads only rows it wrote) -> stays L2-resident with no fences.
// pv: per-block slots (chunk-owned, plain overwrite) in ping-pong A/B
// buffers; readers sum 16 slots in fixed order -> bit-deterministic.
__global__ __launch_bounds__(512) void sinkhorn_coop(const float* __restrict__ u,
                                                     const float* __restrict__ la,
                                                     unsigned short* __restrict__ Kb,
                                                     float* __restrict__ pvA,
                                                     float* __restrict__ pvB,
                                                     unsigned short* __restrict__ Pt,
                                                     unsigned* __restrict__ cnt) {
  int bid = blockIdx.x;
  int tid = threadIdx.x;
  int l = tid & 63, w = tid >> 6;          // 8 waves
  int mloc = bid & 15;
  int ch = bid >> 4;
  int r0 = ch << 6;

  __shared__ float smem[8][1024];          // 32 KB wave col-partials
  __shared__ float v_lds[1024];
  __shared__ float u_lds[64];
  __shared__ unsigned short tile[64][66];

  for (int g = 0; g < 2; ++g) {
    int mat = g * 16 + mloc;
    const float* ub = u + (size_t)mat * NN;
    unsigned short* Ks = Kb + (size_t)mat * NN;
    float* pA = pvA + ((size_t)mat << 14);         // 16 chunks x 1024 floats
    float* pB = pvB + ((size_t)mat << 14);
    unsigned* c = cnt + (size_t)mat * 1024;        // 4 KB stride per matrix

    // ---- phase 0: gumbel -> K bf16; col partials (u-potential = 1) -> pvA
    {
      float colacc[16];
#pragma unroll
      for (int k2 = 0; k2 < 16; ++k2) colacc[k2] = 0.f;
#pragma unroll 1
      for (int p = 0; p < 8; ++p) {
        int row = r0 + (p << 3) + w;
        const f32x4* u4 = (const f32x4*)(ub + (size_t)row * 1024 + l * 16);
        const f32x4* la4 = (const f32x4*)(la + (size_t)row * 1024 + l * 16);
        float kf[16];
#pragma unroll
        for (int q = 0; q < 4; ++q) {
          f32x4 uv = __builtin_nontemporal_load(u4 + q);
          f32x4 lv = __builtin_nontemporal_load(la4 + q);
#pragma unroll
          for (int e = 0; e < 4; ++e)
            kf[q * 4 + e] = expf(lv[e]) / (EPS - logf(uv[e] + EPS));
        }
        bf16x8 o0, o1;
#pragma unroll
        for (int j = 0; j < 8; ++j) {
          o0[j] = (short)f2bf(kf[j]);
          o1[j] = (short)f2bf(kf[8 + j]);
          colacc[j] += kf[j];
          colacc[8 + j] += kf[8 + j];
        }
        bf16x8* kp = (bf16x8*)(Ks + (size_t)row * 1024 + l * 16);
        kp[0] = o0; kp[1] = o1;
      }
#pragma unroll
      for (int k2 = 0; k2 < 16; ++k2) smem[w][l * 16 + k2] = colacc[k2];
      __syncthreads();
      if (tid < 256) {
        float4 s = make_float4(0.f, 0.f, 0.f, 0.f);
#pragma unroll
        for (int ww = 0; ww < 8; ++ww) {
          float4 a = *(float4*)&smem[ww][tid * 4];
          s.x += a.x; s.y += a.y; s.z += a.z; s.w += a.w;
        }
        float* slot = pA + (ch << 10);
        pv_store2(&slot[tid * 4], s.x, s.y);
        pv_store2(&slot[tid * 4 + 2], s.z, s.w);
      }
      mat_barrier(c, 16u);
    }

    // ---- 19 fused iterations (v_t, u_t, col partials for v_{t+1})
    const float* pin = pA;
    float* pout = pB;
#pragma unroll 1
    for (int t = 1; t < NITERS; ++t) {
      {
        // deterministic: sum 16 chunk slots in fixed order; cols 2tid,2tid+1
        float2 s = make_float2(0.f, 0.f);
#pragma unroll
        for (int cc = 0; cc < 16; ++cc) {
          float2 a = pv_load2(pin + (cc << 10) + 2 * tid);
          s.x += a.x; s.y += a.y;
        }
        v_lds[2 * tid] = 1.f / s.x;
        v_lds[2 * tid + 1] = 1.f / s.y;
      }
      __syncthreads();
      float vreg[16];
#pragma unroll
      for (int k2 = 0; k2 < 16; ++k2) vreg[k2] = v_lds[l * 16 + k2];

      float colacc[16];
#pragma unroll
      for (int k2 = 0; k2 < 16; ++k2) colacc[k2] = 0.f;
#pragma unroll 2
      for (int p = 0; p < 8; ++p) {
        int row = r0 + (p << 3) + w;
        const bf16x8* kp = (const bf16x8*)(Ks + (size_t)row * 1024 + l * 16);
        bf16x8 k0 = kp[0], k1 = kp[1];
        float kf[16];
#pragma unroll
        for (int j = 0; j < 8; ++j) { kf[j] = bf2f(k0[j]); kf[8 + j] = bf2f(k1[j]); }
        float dot = 0.f;
#pragma unroll
        for (int k2 = 0; k2 < 16; ++k2) dot += kf[k2] * vreg[k2];
#pragma unroll
        for (int m = 1; m < 64; m <<= 1) dot += __shfl_xor(dot, m, 64);
        float ui = 1.0f / dot;
#pragma unroll
        for (int k2 = 0; k2 < 16; ++k2) colacc[k2] += kf[k2] * ui;
      }
#pragma unroll
      for (int k2 = 0; k2 < 16; ++k2) smem[w][l * 16 + k2] = colacc[k2];
      __syncthreads();
      if (tid < 256) {
        float4 s = make_float4(0.f, 0.f, 0.f, 0.f);
#pragma unroll
        for (int ww = 0; ww < 8; ++ww) {
          float4 a = *(float4*)&smem[ww][tid * 4];
          s.x += a.x; s.y += a.y; s.z += a.z; s.w += a.w;
        }
        float* slot = pout + (ch << 10);
        pv_store2(&slot[tid * 4], s.x, s.y);
        pv_store2(&slot[tid * 4 + 2], s.z, s.w);
      }
      mat_barrier(c, 16u * (unsigned)(t + 1));
      float* tp = pout; pout = (float*)pin; pin = tp;
    }

    // ---- final: v_20, u_20, Pt[m][n] = K[n][m] * u[n] * v[m] (bf16)
    {
      float2 s = make_float2(0.f, 0.f);
#pragma unroll
      for (int cc = 0; cc < 16; ++cc) {
        float2 a = pv_load2(pin + (cc << 10) + 2 * tid);
        s.x += a.x; s.y += a.y;
      }
      v_lds[2 * tid] = 1.f / s.x;
      v_lds[2 * tid + 1] = 1.f / s.y;
    }
    __syncthreads();
    {
      float vreg[16];
#pragma unroll
      for (int k2 = 0; k2 < 16; ++k2) vreg[k2] = v_lds[l * 16 + k2];
#pragma unroll 1
      for (int p = 0; p < 8; ++p) {
        int row = r0 + (p << 3) + w;
        const bf16x8* kp = (const bf16x8*)(Ks + (size_t)row * 1024 + l * 16);
        bf16x8 k0 = kp[0], k1 = kp[1];
        float dot = 0.f;
#pragma unroll
        for (int j = 0; j < 8; ++j) dot += bf2f(k0[j]) * vreg[j] + bf2f(k1[j]) * vreg[8 + j];
#pragma unroll
        for (int m = 1; m < 64; m <<= 1) dot += __shfl_xor(dot, m, 64);
        if (l == 0) u_lds[(p << 3) + w] = 1.0f / dot;
      }
    }
    __syncthreads();
    {
      unsigned short* Pb = Pt + (size_t)mat * NN;
      int cc = tid & 63, r8 = tid >> 6;
#pragma unroll 1
      for (int mt = 0; mt < 16; ++mt) {
        int m0 = mt << 6;
#pragma unroll
        for (int p = 0; p < 8; ++p) {
          int rr = (p << 3) + r8;
          float val = bf2f((short)Ks[(size_t)(r0 + rr) * 1024 + m0 + cc]) * u_lds[rr] * v_lds[m0 + cc];
          tile[rr][cc] = f2bf(val);
        }
        __syncthreads();
#pragma unroll
        for (int p = 0; p < 8; ++p) {
          int rr = (p << 3) + r8;
          Pb[(size_t)(m0 + rr) * 1024 + r0 + cc] = tile[cc][rr];
        }
        __syncthreads();
      }
    }
  }
}

// ---------------------------------------------------------------------------
__global__ __launch_bounds__(256) void cvt_x(const float4* __restrict__ x4,
                                             unsigned short* __restrict__ xb) {
  int gid = blockIdx.x * 256 + threadIdx.x;      // 2,097,152 float4s
  float4 v = x4[gid];
  ushort4 o;
  o.x = f2bf(v.x); o.y = f2bf(v.y); o.z = f2bf(v.z); o.w = f2bf(v.w);
  *(ushort4*)&xb[(size_t)gid * 4] = o;
}

// C[d][m] = sum_n A[d][n] * B[n][m]; A = xb (row-major), Bt = P^T.
// 128x128 tile, 4 waves, 16x16x32 MFMA, global_load_lds(16B), XCD swizzle.
__global__ __launch_bounds__(256) void gemm_bf16(const unsigned short* __restrict__ xb,
                                                 const unsigned short* __restrict__ Pt,
                                                 float* __restrict__ out) {
  int bid = blockIdx.x;                          // 2048 = 8 XCD * 256
  int lid = (bid & 7) * 256 + (bid >> 3);        // bijective XCD swizzle
  int sb = lid >> 6;
  int tm = (lid >> 3) & 7;
  int tn = lid & 7;
  int b = sb & 7;
  const unsigned short* A = xb + (size_t)b * NN;
  const unsigned short* Bt = Pt + (size_t)sb * NN;
  float* C = out + (size_t)sb * NN;

  __shared__ unsigned short lA[128 * 32];
  __shared__ unsigned short lB[128 * 32];

  int tid = threadIdx.x;
  int lane = tid & 63;
  int w = tid >> 6;
  int wm = (w >> 1) << 6;
  int wn = (w & 1) << 6;

  f32x4 acc[4][4] = {};

  int lr = tid >> 2;
  int lk = (tid & 3) << 3;
  const unsigned short* gA0 = A + (size_t)(tm * 128 + lr) * 1024 + lk;
  const unsigned short* gB0 = Bt + (size_t)(tn * 128 + lr) * 1024 + lk;

  for (int k0 = 0; k0 < 1024; k0 += 32) {
    __builtin_amdgcn_global_load_lds((const __attribute__((address_space(1))) void*)(gA0 + k0),
                                     (__attribute__((address_space(3))) void*)&lA[tid * 8], 16, 0, 0);
    __builtin_amdgcn_global_load_lds((const __attribute__((address_space(1))) void*)(gA0 + 64 * 1024 + k0),
                                     (__attribute__((address_space(3))) void*)&lA[2048 + tid * 8], 16, 0, 0);
    __builtin_amdgcn_global_load_lds((const __attribute__((address_space(1))) void*)(gB0 + k0),
                                     (__attribute__((address_space(3))) void*)&lB[tid * 8], 16, 0, 0);
    __builtin_amdgcn_global_load_lds((const __attribute__((address_space(1))) void*)(gB0 + 64 * 1024 + k0),
                                     (__attribute__((address_space(3))) void*)&lB[2048 + tid * 8], 16, 0, 0);
    __syncthreads();

    int kg = (lane >> 4) << 3;
    int rr = lane & 15;
    bf16x8 af[4], bfr[4];
#pragma unroll
    for (int mt = 0; mt < 4; ++mt)
      af[mt] = *(const bf16x8*)&lA[(wm + mt * 16 + rr) * 32 + kg];
#pragma unroll
    for (int nt = 0; nt < 4; ++nt)
      bfr[nt] = *(const bf16x8*)&lB[(wn + nt * 16 + rr) * 32 + kg];
#pragma unroll
    for (int mt = 0; mt < 4; ++mt)
#pragma unroll
      for (int nt = 0; nt < 4; ++nt)
        acc[mt][nt] = __builtin_amdgcn_mfma_f32_16x16x32_bf16(af[mt], bfr[nt], acc[mt][nt], 0, 0, 0);
    __syncthreads();
  }

  int col0 = lane & 15;
  int row0 = (lane >> 4) << 2;
#pragma unroll
  for (int mt = 0; mt < 4; ++mt) {
#pragma unroll
    for (int nt = 0; nt < 4; ++nt) {
      int row = tm * 128 + wm + mt * 16 + row0;
      int col = tn * 128 + wn + nt * 16 + col0;
#pragma unroll
      for (int r = 0; r < 4; ++r)
        C[(size_t)(row + r) * 1024 + col] = acc[mt][nt][r];
    }
  }
}

extern "C" void kernel_launch(void* const* d_in, const int* in_sizes, int n_in,
                              void* d_out, int out_size, void* d_ws, size_t ws_size,
                              hipStream_t stream) {
  (void)in_sizes; (void)n_in; (void)out_size;
  const float* x  = (const float*)d_in[0];   // (B=8, D=1024, N=1024)
  const float* la = (const float*)d_in[1];   // (N, N)
  const float* u  = (const float*)d_in[2];   // (S=4, B=8, N, N)
  float* out = (float*)d_out;                // (S, B, D, N)

  char* ws = (char*)d_ws;
  unsigned short* Kb = (unsigned short*)(ws);               // 64 MiB bf16 K
  unsigned short* Pt = (unsigned short*)(ws + 67108864);    // 64 MiB bf16 P^T
  unsigned short* xb = (unsigned short*)(ws + 134217728);   // 16 MiB bf16 x
  float* pvA         = (float*)(ws + 150994944);            // 2 MiB per-block slots
  float* pvB         = (float*)(ws + 153092096);            // 2 MiB per-block slots
  unsigned* cnt      = (unsigned*)(ws + 155189248);         // 128 KiB sync (4KB/matrix)
  if (ws_size < 155320320) return;  // fail loudly rather than corrupt

  hipMemsetAsync((void*)cnt, 0, 131072, stream);
  cvt_x<<<8192, 256, 0, stream>>>((const float4*)x, xb);

  void* args[] = {(void*)&u, (void*)&la, (void*)&Kb, (void*)&pvA,
                  (void*)&pvB, (void*)&Pt, (void*)&cnt};
  hipLaunchCooperativeKernel((void*)sinkhorn_coop, dim3(256), dim3(512),
                             args, 0, stream);

  gemm_bf16<<<2048, 256, 0, stream>>>(xb, Pt, out);
}